// Round 7
// baseline (1085.801 us; speedup 1.0000x reference)
//
#include <hip/hip_runtime.h>
#include <float.h>

#define B8 8
#define NPTS 4096

// ---------------- split x[B,6,N] -> xyz[B,N,3], nrm[B,N,3], xyz4[B,N,4] ----------------
// xyz4.w = x*x + y*y + z*z (same expression order knn20 used inline -> bitwise same)
__global__ void split_xyz_kernel(const float* __restrict__ x,
                                 float* __restrict__ xyz, float* __restrict__ nrm,
                                 float4* __restrict__ xyz4) {
#pragma clang fp contract(off)
  int g = blockIdx.x * 256 + threadIdx.x;
  if (g >= B8 * NPTS) return;
  int b = g / NPTS, n = g % NPTS;
  const float* xb = x + (size_t)b * 6 * NPTS;
  float* o1 = xyz + (size_t)g * 3;
  float* o2 = nrm + (size_t)g * 3;
  float a0 = xb[0 * NPTS + n], a1 = xb[1 * NPTS + n], a2 = xb[2 * NPTS + n];
  o1[0] = a0; o1[1] = a1; o1[2] = a2;
  xyz4[g] = make_float4(a0, a1, a2, a0 * a0 + a1 * a1 + a2 * a2);
  o2[0] = xb[3 * NPTS + n]; o2[1] = xb[4 * NPTS + n]; o2[2] = xb[5 * NPTS + n];
}

// ---------------- DPP helpers ----------------
template <int CTRL, int RM>
__device__ __forceinline__ unsigned dppmov(unsigned v) {
  return (unsigned)__builtin_amdgcn_update_dpp((int)v, (int)v, CTRL, RM, 0xf, false);
}

template <int CTRL, int RM>
__device__ __forceinline__ void red_key_max(unsigned& kh, unsigned& kl) {
  unsigned oh = dppmov<CTRL, RM>(kh);
  unsigned ol = dppmov<CTRL, RM>(kl);
  unsigned long long ko = ((unsigned long long)oh << 32) | ol;
  unsigned long long k  = ((unsigned long long)kh << 32) | kl;
  bool c = ko > k;
  kh = c ? oh : kh;
  kl = c ? ol : kl;
}

template <int CTRL, int RM>
__device__ __forceinline__ void red_key_min(unsigned& kh, unsigned& kl) {
  unsigned oh = dppmov<CTRL, RM>(kh);
  unsigned ol = dppmov<CTRL, RM>(kl);
  unsigned long long ko = ((unsigned long long)oh << 32) | ol;
  unsigned long long k  = ((unsigned long long)kh << 32) | kl;
  bool c = ko < k;
  kh = c ? oh : kh;
  kl = c ? ol : kl;
}

#define WAVE_RED_MAX(kh, kl)            \
  red_key_max<0x111, 0xf>(kh, kl);      \
  red_key_max<0x112, 0xf>(kh, kl);      \
  red_key_max<0x114, 0xf>(kh, kl);      \
  red_key_max<0x118, 0xf>(kh, kl);      \
  red_key_max<0x142, 0xa>(kh, kl);      \
  red_key_max<0x143, 0xc>(kh, kl);

#define WAVE_RED_MIN(kh, kl)            \
  red_key_min<0x111, 0xf>(kh, kl);      \
  red_key_min<0x112, 0xf>(kh, kl);      \
  red_key_min<0x114, 0xf>(kh, kl);      \
  red_key_min<0x118, 0xf>(kh, kl);      \
  red_key_min<0x142, 0xa>(kh, kl);      \
  red_key_min<0x143, 0xc>(kh, kl);

// ---------------- FPS (SA1 only; deeper levels are prefixes of x1) ----------------
// R1/R2: multi-wave configs replicate per-wave fixed VALU faster than they fill
// the serial gap -> BLOCK=256/P=16 is the structural optimum (measured 320us).
template <int BLOCK, int P>
__global__ __launch_bounds__(BLOCK) void fps4_kernel(const float* __restrict__ xyz,
                                                     int N, int S,
                                                     float* __restrict__ out_xyz) {
#pragma clang fp contract(off)
  constexpr int NW = BLOCK / 64;
  __shared__ float4 pts[BLOCK * P];
  __shared__ float4 sel[512];
  __shared__ alignas(16) unsigned long long wkey[2][NW];
  int b = blockIdx.x, t = threadIdx.x;
  const float* p = xyz + (size_t)b * N * 3;
  float px[P], py[P], pz[P], dist[P];
#pragma unroll
  for (int j = 0; j < P; ++j) {
    int idx = t + j * BLOCK;
    float a = p[3 * idx], bb = p[3 * idx + 1], c = p[3 * idx + 2];
    px[j] = a; py[j] = bb; pz[j] = c;
    pts[idx] = make_float4(a, bb, c, 0.f);
    dist[j] = 1e10f;
  }
  __syncthreads();
  float fx = p[0], fy = p[1], fz = p[2];
  for (int i = 0; i < S; ++i) {
    if (t == 0) sel[i] = make_float4(fx, fy, fz, 0.f);
    float bv = -1.0f;
    int bj = 0;
#pragma unroll
    for (int j = 0; j < P; ++j) {
      float dx = px[j] - fx, dy = py[j] - fy, dz = pz[j] - fz;
      float d = dx * dx + dy * dy + dz * dz;
      float nd = fminf(dist[j], d);
      dist[j] = nd;
      bool c = nd > bv;
      bv = c ? nd : bv;
      bj = c ? j : bj;
    }
    unsigned kh = __float_as_uint(bv);
    unsigned kl = (unsigned)(~(t + bj * BLOCK));
    WAVE_RED_MAX(kh, kl);
    int buf = i & 1;
    if ((t & 63) == 63)
      wkey[buf][t >> 6] = ((unsigned long long)kh << 32) | kl;
    __syncthreads();
    unsigned long long g = 0ull;
    const ulonglong2* wk2 = (const ulonglong2*)&wkey[buf][0];
#pragma unroll
    for (int w = 0; w < NW / 2; ++w) {
      ulonglong2 e = wk2[w];
      unsigned long long m = (e.x > e.y) ? e.x : e.y;
      g = (m > g) ? m : g;
    }
    int far = (int)~(unsigned)g;
    float4 f = pts[far];
    fx = f.x; fy = f.y; fz = f.z;
  }
  __syncthreads();
  for (int i = t; i < S; i += BLOCK) {
    float4 f = sel[i];
    float* o = out_xyz + ((size_t)b * S + i) * 3;
    o[0] = f.x; o[1] = f.y; o[2] = f.z;
  }
}

// ---------------- kNN k=20 for SA1 (M=4096, one wave/block) ----------------
// R6: per-lane (min1,min2) cache; owner lane promotes/rescans. Ordering
// semantics identical to full rescan (ascending index, strict <, 64-bit key).
__global__ __launch_bounds__(64) void knn20_kernel(const float* __restrict__ q,
                                                   const float4* __restrict__ ref4,
                                                   int* __restrict__ nidx) {
#pragma clang fp contract(off)
  int bs = blockIdx.x;                 // b*512 + s
  int b = bs >> 9;
  int t = threadIdx.x;
  __shared__ float sd[4096];
  const float* qp = q + (size_t)bs * 3;
  float qx = qp[0], qy = qp[1], qz = qp[2];
  float qq = qx * qx + qy * qy + qz * qz;
  const float4* rp = ref4 + (size_t)b * 4096;
  float v1 = FLT_MAX, v2 = FLT_MAX;
  int i1 = 0, i2 = 0;
  for (int k = 0; k < 64; ++k) {
    int i = t + (k << 6);
    float4 r = rp[i];
    float dot = qx * r.x + qy * r.y + qz * r.z;
    float d = qq - 2.0f * dot + r.w;
    sd[i] = d;
    if (d < v1) { v2 = v1; i2 = i1; v1 = d; i1 = i; }
    else if (d < v2) { v2 = d; i2 = i; }
  }
  __syncthreads();
  unsigned keep = 0;
  for (int k = 0; k < 20; ++k) {
    unsigned kh = __float_as_uint(v1), kl = (unsigned)i1;
    WAVE_RED_MIN(kh, kl);
    unsigned w = (unsigned)__builtin_amdgcn_readlane((int)kl, 63);
    if (t == k) keep = w;
    if (t == 0) sd[w] = FLT_MAX;
    __syncthreads();                   // sd[w] visible before any rescan
    if (((int)w & 63) == t) {          // I owned the winner (w == my i1)
      v1 = v2; i1 = i2;
      v2 = FLT_MAX; i2 = 0;
      if (v1 == FLT_MAX) {             // cache exhausted: rebuild from sd
        for (int kk = 0; kk < 64; ++kk) {
          int i = t + (kk << 6);
          float d = sd[i];
          if (d < v1) { v2 = v1; i2 = i1; v1 = d; i1 = i; }
          else if (d < v2) { v2 = d; i2 = i; }
        }
      }
    }
  }
  if (t < 20) nidx[(size_t)bs * 20 + t] = (int)keep;
}

// ---------------- SA1 direct kernel (K=6 too small for the GEMM path) ----------------
__global__ __launch_bounds__(256) void sa1_kernel(
    const float* __restrict__ xyz, const float* __restrict__ nrm,
    const float* __restrict__ x1, const int* __restrict__ nidx,
    const float* __restrict__ W, const float* __restrict__ bias,
    float* __restrict__ f1) {
#pragma clang fp contract(off)
  __shared__ alignas(16) float smem_in[4][20][8];
  int wv = threadIdx.x >> 6, t = threadIdx.x & 63;
  int g = blockIdx.x * 4 + wv;         // group in [0, 4096)
  int b = g >> 9;
  if (t < 20) {
    int id = nidx[(size_t)g * 20 + t];
    const float* xr = xyz + ((size_t)b * 4096 + id) * 3;
    const float* xq = x1 + (size_t)g * 3;        // b*512+s == g
    const float* nr = nrm + ((size_t)b * 4096 + id) * 3;
    smem_in[wv][t][0] = xr[0] - xq[0];
    smem_in[wv][t][1] = xr[1] - xq[1];
    smem_in[wv][t][2] = xr[2] - xq[2];
    smem_in[wv][t][3] = nr[0];
    smem_in[wv][t][4] = nr[1];
    smem_in[wv][t][5] = nr[2];
    smem_in[wv][t][6] = 0.0f;
    smem_in[wv][t][7] = 0.0f;
  }
  __syncthreads();
  float w0 = W[0 * 64 + t], w1 = W[1 * 64 + t], w2 = W[2 * 64 + t];
  float w3 = W[3 * 64 + t], w4 = W[4 * 64 + t], w5 = W[5 * 64 + t];
  float bb = bias[t];
  float m = 0.0f;                      // relu >= 0: 0-init absorbs the relu clamp
  for (int n = 0; n < 20; ++n) {
    const float4 a = *reinterpret_cast<const float4*>(&smem_in[wv][n][0]);
    const float4 c = *reinterpret_cast<const float4*>(&smem_in[wv][n][4]);
    float v = a.x * w0;
    v += a.y * w1;
    v += a.z * w2;
    v += a.w * w3;
    v += c.x * w4;
    v += c.y * w5;
    v += bb;
    m = fmaxf(m, v);
  }
  f1[(size_t)g * 64 + t] = m;
}

// ---------------- knn3 select+store helper ----------------
__device__ __forceinline__ void knn3_store(int g, const float* rx3,
                                           float qx, float qy, float qz,
                                           int i0, int i1, int i2,
                                           int* __restrict__ idx3,
                                           float* __restrict__ w3) {
#pragma clang fp contract(off)
  int ii[3] = {i0, i1, i2};
  float w[3];
  float wsum = 0.0f;
#pragma unroll
  for (int k = 0; k < 3; ++k) {
    const float* r = rx3 + (size_t)ii[k] * 3;
    float dx = r[0] - qx, dy = r[1] - qy, dz = r[2] - qz;
    float d = dx * dx + dy * dy + dz * dz;
    w[k] = 1.0f / (d + 1e-8f);
    wsum += w[k];
  }
#pragma unroll
  for (int k = 0; k < 3; ++k) {
    idx3[(size_t)g * 3 + k] = ii[k];
    w3[(size_t)g * 3 + k] = w[k] / wsum;
  }
}

// ---------------- fused neighbor kernel: SA2/3/4 knn20 + all knn3 ----------------
__global__ __launch_bounds__(256) void neighbors_kernel(
    const float* __restrict__ xyz, const float* __restrict__ x1,
    int* __restrict__ nidx2, int* __restrict__ nidx3, int* __restrict__ nidx4,
    int* __restrict__ idx3_3, float* __restrict__ w3_3,
    int* __restrict__ idx3_2, float* __restrict__ w3_2,
    int* __restrict__ idx3_1, float* __restrict__ w3_1,
    int* __restrict__ idx3_0, float* __restrict__ w3_0) {
#pragma clang fp contract(off)
  __shared__ float4 smem4[512];          // 8 KB, aliased per region
  int blk = blockIdx.x, tid = threadIdx.x;

  if (blk < 896) {  // ---- knn20 regions ----
    int S, M, qid;
    int* nout;
    const int wv = tid >> 6, t64 = tid & 63;
    if (blk < 512)      { S = 256; M = 512; qid = blk * 4 + wv;         nout = nidx2; }
    else if (blk < 768) { S = 128; M = 256; qid = (blk - 512) * 4 + wv; nout = nidx3; }
    else                { S = 64;  M = 128; qid = (blk - 768) * 4 + wv; nout = nidx4; }
    float* swd = (float*)smem4 + wv * M;
    int b = qid / S, s = qid % S;
    const float* qp = x1 + ((size_t)b * 512 + s) * 3;
    float qx = qp[0], qy = qp[1], qz = qp[2];
    float qq = qx * qx + qy * qy + qz * qz;
    const float* rp = x1 + (size_t)b * 512 * 3;
    for (int i = t64; i < M; i += 64) {
      float rx = rp[3 * i], ry = rp[3 * i + 1], rz = rp[3 * i + 2];
      float rr = rx * rx + ry * ry + rz * rz;
      float dot = qx * rx + qy * ry + qz * rz;
      swd[i] = qq - 2.0f * dot + rr;
    }
    __syncthreads();
    unsigned keep = 0;
    for (int k = 0; k < 20; ++k) {
      float bv = FLT_MAX;
      int bi = 0;
      for (int i = t64; i < M; i += 64) {
        float v = swd[i];
        bool c = v < bv;
        bv = c ? v : bv;
        bi = c ? i : bi;
      }
      unsigned kh = __float_as_uint(bv), kl = (unsigned)bi;
      WAVE_RED_MIN(kh, kl);
      unsigned w = (unsigned)__builtin_amdgcn_readlane((int)kl, 63);
      if (t64 == k) keep = w;
      if (t64 == 0) swd[w] = FLT_MAX;
      __syncthreads();   // uniform across the block's 4 waves (same trip count)
    }
    if (t64 < 20) nout[(size_t)qid * 20 + t64] = (int)keep;
    return;
  }

  if (blk < 900) {  // ---- FP3 knn3, plain VMEM scan (M=64) ----
    int g = (blk - 896) * 256 + tid;     // < 1024
    int Sq = 128, M = 64;
    int b = g / Sq, s = g % Sq;
    const float* qp = x1 + ((size_t)b * 512 + s) * 3;
    float qx = qp[0], qy = qp[1], qz = qp[2];
    float qq = qx * qx + qy * qy + qz * qz;
    const float* rp = x1 + (size_t)b * 512 * 3;
    float v0 = FLT_MAX, v1 = FLT_MAX, v2 = FLT_MAX;
    int i0 = 0, i1 = 0, i2 = 0;
    for (int i = 0; i < M; ++i) {
      float rx = rp[3 * i], ry = rp[3 * i + 1], rz = rp[3 * i + 2];
      float d = qq - 2.0f * (qx * rx + qy * ry + qz * rz) + (rx * rx + ry * ry + rz * rz);
      if (d < v2) {
        if (d < v1) {
          if (d < v0) { v2 = v1; i2 = i1; v1 = v0; i1 = i0; v0 = d; i0 = i; }
          else { v2 = v1; i2 = i1; v1 = d; i1 = i; }
        } else { v2 = d; i2 = i; }
      }
    }
    knn3_store(g, rp, qx, qy, qz, i0, i1, i2, idx3_3, w3_3);
    return;
  }

  // ---- knn3 LDS regions (block-uniform batch) ----
  int g, Sq, M, LDQ;
  int* oidx;
  float* ow;
  const float* q;
  if (blk < 908)      { g = (blk - 900) * 256 + tid; Sq = 256;  M = 128; oidx = idx3_2; ow = w3_2; q = x1;  LDQ = 512; }
  else if (blk < 924) { g = (blk - 908) * 256 + tid; Sq = 512;  M = 256; oidx = idx3_1; ow = w3_1; q = x1;  LDQ = 512; }
  else                { g = (blk - 924) * 256 + tid; Sq = 4096; M = 512; oidx = idx3_0; ow = w3_0; q = xyz; LDQ = 4096; }
  int b = g / Sq, s = g % Sq;
  const float* rp = x1 + (size_t)b * 512 * 3;
  for (int i = tid; i < M; i += 256) {
    float rx = rp[3 * i], ry = rp[3 * i + 1], rz = rp[3 * i + 2];
    smem4[i] = make_float4(rx, ry, rz, rx * rx + ry * ry + rz * rz);
  }
  __syncthreads();
  const float* qp = q + ((size_t)b * LDQ + s) * 3;
  float qx = qp[0], qy = qp[1], qz = qp[2];
  float qq = qx * qx + qy * qy + qz * qz;
  float v0 = FLT_MAX, v1 = FLT_MAX, v2 = FLT_MAX;
  int i0 = 0, i1 = 0, i2 = 0;
  for (int i = 0; i < M; ++i) {
    float4 r = smem4[i];
    float d = qq - 2.0f * (qx * r.x + qy * r.y + qz * r.z) + r.w;
    if (d < v2) {
      if (d < v1) {
        if (d < v0) { v2 = v1; i2 = i1; v1 = v0; i1 = i0; v0 = d; i0 = i; }
        else { v2 = v1; i2 = i1; v1 = d; i1 = i; }
      } else { v2 = d; i2 = i; }
    }
  }
  {
    int ii[3] = {i0, i1, i2};
    float w[3];
    float wsum = 0.0f;
#pragma unroll
    for (int k = 0; k < 3; ++k) {
      float4 r = smem4[ii[k]];
      float dx = r.x - qx, dy = r.y - qy, dz = r.z - qz;
      float d = dx * dx + dy * dy + dz * dz;
      w[k] = 1.0f / (d + 1e-8f);
      wsum += w[k];
    }
#pragma unroll
    for (int k = 0; k < 3; ++k) {
      oidx[(size_t)g * 3 + k] = ii[k];
      ow[(size_t)g * 3 + k] = w[k] / wsum;
    }
  }
}

// ---------------- GEMM core R7: 128x64 tile, 8x4 acc, BK=16, double-buffered ----
// All Mrows are multiples of 128. Thread: row-octet A-staging (one row, 8
// consecutive k), one float4 B-stage. Compute: acc[8][4] per thread.
// FMA:LDS issue per kk = 64cy:36cy (was 32:24); barriers/FLOP halved.
#define GEMM_STAGE(k0v, ...)                                                      \
    {                                                                             \
      int r_ = (int)threadIdx.x & 127;                                            \
      int rr = rowBase + r_;                                                      \
      int kq0 = (k0v) + (((int)threadIdx.x >> 7) << 3);                           \
      if (rr < Mrows) { __VA_ARGS__ }                                             \
      else {                                                                      \
        _Pragma("unroll")                                                         \
        for (int c_ = 0; c_ < 8; ++c_) areg8[c_] = 0.0f;                          \
      }                                                                           \
    }                                                                             \
    {                                                                             \
      int kk = (int)threadIdx.x >> 4;                                             \
      int n4 = ((int)threadIdx.x & 15) * 4;                                       \
      int kq = (k0v) + kk, cc = colBase + n4;                                     \
      if (colBase + 64 <= N) {                                                    \
        if (kq < K) breg4 = *reinterpret_cast<const float4*>(&Wm[(size_t)kq * N + cc]); \
        else breg4 = make_float4(0.f, 0.f, 0.f, 0.f);                             \
      } else {                                                                    \
        breg4.x = (kq < K && cc < N) ? Wm[(size_t)kq * N + cc] : 0.0f;            \
        breg4.y = (kq < K && cc + 1 < N) ? Wm[(size_t)kq * N + cc + 1] : 0.0f;    \
        breg4.z = (kq < K && cc + 2 < N) ? Wm[(size_t)kq * N + cc + 2] : 0.0f;    \
        breg4.w = (kq < K && cc + 3 < N) ? Wm[(size_t)kq * N + cc + 3] : 0.0f;    \
      }                                                                           \
    }

#define GEMM_WRITE_LDS(bufv)                                                      \
    {                                                                             \
      int r_ = (int)threadIdx.x & 127;                                            \
      int k8_ = (((int)threadIdx.x >> 7) << 3);                                   \
      _Pragma("unroll")                                                           \
      for (int c_ = 0; c_ < 8; ++c_) As[bufv][k8_ + c_][r_] = areg8[c_];          \
    }                                                                             \
    *reinterpret_cast<float4*>(&Bs[bufv][threadIdx.x >> 4][(threadIdx.x & 15) * 4]) = breg4;

#define GEMM_MAIN(...)                                                            \
  __shared__ alignas(16) float As[2][16][132];                                    \
  __shared__ alignas(16) float Bs[2][16][64];                                     \
  int tx = threadIdx.x & 15, ty = threadIdx.x >> 4;                               \
  int rowBase = blockIdx.y * 128;                                                 \
  int colBase = blockIdx.x * 64;                                                  \
  float acc[8][4] = {};                                                           \
  float areg8[8];                                                                 \
  float4 breg4;                                                                   \
  GEMM_STAGE(kLo, __VA_ARGS__)                                                    \
  GEMM_WRITE_LDS(0)                                                               \
  __syncthreads();                                                                \
  int cur = 0;                                                                    \
  for (int k0 = kLo; k0 < kHi; k0 += 16) {                                        \
    int nxt = cur ^ 1;                                                            \
    bool more = (k0 + 16 < kHi);                                                  \
    if (more) { GEMM_STAGE(k0 + 16, __VA_ARGS__) }                                \
    _Pragma("unroll")                                                             \
    for (int kk = 0; kk < 16; ++kk) {                                             \
      const float4 av0 = *reinterpret_cast<const float4*>(&As[cur][kk][ty * 8]);  \
      const float4 av1 = *reinterpret_cast<const float4*>(&As[cur][kk][ty * 8 + 4]); \
      const float4 bv = *reinterpret_cast<const float4*>(&Bs[cur][kk][tx * 4]);   \
      float a8_[8] = {av0.x, av0.y, av0.z, av0.w, av1.x, av1.y, av1.z, av1.w};    \
      float b4_[4] = {bv.x, bv.y, bv.z, bv.w};                                    \
      _Pragma("unroll")                                                           \
      for (int i_ = 0; i_ < 8; ++i_) {                                            \
        _Pragma("unroll")                                                         \
        for (int j_ = 0; j_ < 4; ++j_) acc[i_][j_] += a8_[i_] * b4_[j_];          \
      }                                                                           \
    }                                                                             \
    if (more) { GEMM_WRITE_LDS(nxt) }                                             \
    __syncthreads();                                                              \
    cur = nxt;                                                                    \
  }

#define GEMM_EPI_STORE                                                            \
  _Pragma("unroll")                                                               \
  for (int i = 0; i < 8; ++i) {                                                   \
    int row = rowBase + ty * 8 + i;                                               \
    if (row >= Mrows) continue;                                                   \
    _Pragma("unroll")                                                             \
    for (int j = 0; j < 4; ++j) {                                                 \
      int col = colBase + tx * 4 + j;                                             \
      if (col >= N) continue;                                                     \
      float v = acc[i][j] + bias[col];                                            \
      if (RELU) v = fmaxf(v, 0.0f);                                               \
      C[(size_t)row * N + col] = v;                                               \
    }                                                                             \
  }

// plain GEMM (seg head; K=128 -> octet loads always in-range and 32B-aligned)
__global__ __launch_bounds__(256) void gemm_kernel(const float* __restrict__ A,
                                                   const float* __restrict__ Wm,
                                                   const float* __restrict__ bias,
                                                   float* __restrict__ C,
                                                   int Mrows, int N, int K, int RELU) {
  const int kLo = 0, kHi = K;
  GEMM_MAIN(
    if (kq0 + 7 < K) {
      float4 u0 = *reinterpret_cast<const float4*>(&A[(size_t)rr * K + kq0]);
      float4 u1 = *reinterpret_cast<const float4*>(&A[(size_t)rr * K + kq0 + 4]);
      areg8[0] = u0.x; areg8[1] = u0.y; areg8[2] = u0.z; areg8[3] = u0.w;
      areg8[4] = u1.x; areg8[5] = u1.y; areg8[6] = u1.z; areg8[7] = u1.w;
    } else {
      _Pragma("unroll")
      for (int c_ = 0; c_ < 8; ++c_) {
        int kq = kq0 + c_;
        areg8[c_] = (kq < K) ? A[(size_t)rr * K + kq] : 0.0f;
      }
    }
  )
  GEMM_EPI_STORE
}

// SA GEMM (SA2-4): fused grouping gather + ReLU + maxpool-over-20 via atomic-max.
// fOut must be zero-initialized; relu >= 0 so float-bit int max == float max.
__global__ __launch_bounds__(256) void gemm_sa_kernel(
    const float* __restrict__ xyz, const float* __restrict__ feats,
    const float* __restrict__ new_xyz, const int* __restrict__ nidx,
    const float* __restrict__ Wm, const float* __restrict__ bias,
    float* __restrict__ fOut, int Mref, int LDR, int S, int LDQ, int Cf,
    int Mrows, int N, int K) {
  const int kLo = 0, kHi = K;
  GEMM_MAIN(
    int bs = rr / 20;
    int s_ = bs % S;
    int b = bs / S;
    int id = nidx[rr];
    const float* xr_ = xyz + ((size_t)b * LDR + id) * 3;
    const float* xq_ = new_xyz + ((size_t)b * LDQ + s_) * 3;
    const float* fb_ = feats + ((size_t)b * Mref + id) * Cf;
    _Pragma("unroll")
    for (int c_ = 0; c_ < 8; ++c_) {
      int kq = kq0 + c_;
      float v = 0.0f;
      if (kq < K) v = (kq < 3) ? (xr_[kq] - xq_[kq]) : fb_[kq - 3];
      areg8[c_] = v;
    }
  )
  // epilogue: 8 consecutive rows span at most 2 groups of 20 -> two register
  // pre-maxes, <=2 LDS atomics per column; 128 rows span <=8 groups.
  __shared__ int smax[8][64];
  int gBase = rowBase / 20;
  int nG = (rowBase + 127) / 20 - gBase + 1;
  for (int l = threadIdx.x; l < nG * 64; l += 256) smax[l >> 6][l & 63] = 0;
  __syncthreads();
  {
    int r0 = rowBase + ty * 8;
    int ga = r0 / 20, gb = (r0 + 7) / 20;     // gb - ga is 0 or 1
    int split = gb * 20 - r0;                  // valid when gb > ga
#pragma unroll
    for (int j = 0; j < 4; ++j) {
      int col = colBase + tx * 4 + j;
      if (col >= N) continue;
      float bb = bias[col];
      float ma = 0.0f, mb = 0.0f;
#pragma unroll
      for (int i = 0; i < 8; ++i) {
        int row = r0 + i;
        if (row >= Mrows) continue;
        float v = fmaxf(acc[i][j] + bb, 0.0f);
        if (gb == ga || i < split) ma = fmaxf(ma, v);
        else mb = fmaxf(mb, v);
      }
      atomicMax(&smax[ga - gBase][tx * 4 + j], __float_as_int(ma));
      if (gb > ga) atomicMax(&smax[gb - gBase][tx * 4 + j], __float_as_int(mb));
    }
  }
  __syncthreads();
  for (int l = threadIdx.x; l < nG * 64; l += 256) {
    int g = gBase + (l >> 6), c = colBase + (l & 63);
    if (c < N && g * 20 < Mrows)
      atomicMax((int*)&fOut[(size_t)g * N + c], smax[l >> 6][l & 63]);
  }
}

// FP GEMM with fused 3-NN interp + skip concat; split-K + consumer finalize.
__global__ __launch_bounds__(256) void gemm_fp_kernel(
    const float* __restrict__ fr, const int* __restrict__ idx3,
    const float* __restrict__ w3, const float* __restrict__ skip,
    const float* __restrict__ cls, const float* __restrict__ xyzq,
    const float* __restrict__ nrmq, const float* __restrict__ frBias,
    const float* __restrict__ Wm, const float* __restrict__ bias,
    float* __restrict__ C, int Sq, int Mr, int Cr, int Cs, int mode,
    int SPLITK, int CHUNK,
    int Mrows, int N, int K) {
  const int kLo = blockIdx.z * CHUNK;
  const int kHi = min(K, kLo + CHUNK);
  GEMM_MAIN(
    int bs = rr;
    int b = bs / Sq;
    const int* ii_ = idx3 + (size_t)bs * 3;
    const float* ww_ = w3 + (size_t)bs * 3;
    int i0_ = ii_[0], i1_ = ii_[1], i2_ = ii_[2];
    float w0_ = ww_[0], w1_ = ww_[1], w2_ = ww_[2];
    const float* fb_ = fr + (size_t)b * Mr * Cr;
    _Pragma("unroll")
    for (int c_ = 0; c_ < 8; ++c_) {
      int kq = kq0 + c_;
      float v = 0.0f;
      if (kq < K) {
        if (kq < Cr) {
          float a0 = fb_[(size_t)i0_ * Cr + kq];
          float a1 = fb_[(size_t)i1_ * Cr + kq];
          float a2 = fb_[(size_t)i2_ * Cr + kq];
          if (frBias) {
            float bb = frBias[kq];
            a0 = fmaxf(a0 + bb, 0.0f);
            a1 = fmaxf(a1 + bb, 0.0f);
            a2 = fmaxf(a2 + bb, 0.0f);
          }
          v = w0_ * a0;
          v += w1_ * a1;
          v += w2_ * a2;
        } else {
          int cc = kq - Cr;
          if (mode == 0) {
            v = skip[(size_t)bs * Cs + cc];
          } else {
            if (cc < 16) v = cls[(size_t)b * 16 + cc];
            else if (cc < 19) v = xyzq[(size_t)bs * 3 + (cc - 16)];
            else v = nrmq[(size_t)bs * 3 + (cc - 19)];
          }
        }
      }
      areg8[c_] = v;
    }
  )
  if (SPLITK) {
#pragma unroll
    for (int i = 0; i < 8; ++i) {
      int row = rowBase + ty * 8 + i;
      if (row >= Mrows) continue;
#pragma unroll
      for (int j = 0; j < 4; ++j) {
        int col = colBase + tx * 4 + j;
        if (col >= N) continue;
        atomicAdd(&C[(size_t)row * N + col], acc[i][j]);
      }
    }
  } else {
    const int RELU = 1;
    GEMM_EPI_STORE
  }
}

// ---------------- transpose g0 [B,N,128] -> out2 [B,128,N] ----------------
__global__ __launch_bounds__(256) void transpose_g0_kernel(const float* __restrict__ g0,
                                                           float* __restrict__ out2) {
  __shared__ float tile[32][33];
  int n0 = blockIdx.x * 32, c0 = blockIdx.y * 32, b = blockIdx.z;
  int tx = threadIdx.x & 31, ty = threadIdx.x >> 5;
#pragma unroll
  for (int j = 0; j < 32; j += 8)
    tile[ty + j][tx] = g0[((size_t)b * NPTS + n0 + ty + j) * 128 + c0 + tx];
  __syncthreads();
#pragma unroll
  for (int j = 0; j < 32; j += 8)
    out2[((size_t)b * 128 + c0 + ty + j) * NPTS + n0 + tx] = tile[tx][ty + j];
}

// ---------------- host-side orchestration ----------------
static inline int cdiv(int a, int b) { return (a + b - 1) / b; }

extern "C" void kernel_launch(void* const* d_in, const int* in_sizes, int n_in,
                              void* d_out, int out_size, void* d_ws, size_t ws_size,
                              hipStream_t stream) {
  const float* x    = (const float*)d_in[0];
  const float* cls  = (const float*)d_in[1];
  const float* W0 = (const float*)d_in[2];  const float* b0 = (const float*)d_in[3];
  const float* W1 = (const float*)d_in[4];  const float* b1 = (const float*)d_in[5];
  const float* W2 = (const float*)d_in[6];  const float* b2 = (const float*)d_in[7];
  const float* W3 = (const float*)d_in[8];  const float* b3 = (const float*)d_in[9];
  const float* F3 = (const float*)d_in[10]; const float* fb3 = (const float*)d_in[11];
  const float* F2 = (const float*)d_in[12]; const float* fb2 = (const float*)d_in[13];
  const float* F1 = (const float*)d_in[14]; const float* fb1 = (const float*)d_in[15];
  const float* F0 = (const float*)d_in[16]; const float* fb0 = (const float*)d_in[17];
  const float* Wseg = (const float*)d_in[18]; const float* bseg = (const float*)d_in[19];
  float* out = (float*)d_out;

  float* ws = (float*)d_ws;
  size_t off = 0;
  auto alloc = [&](size_t n) { float* p = ws + off; off += (n + 3) & ~(size_t)3; return p; };
  float* xyz = alloc(8 * 4096 * 3);
  float* nrm = alloc(8 * 4096 * 3);
  float4* xyz4 = (float4*)alloc(8 * 4096 * 4);   // (x,y,z,|p|^2) for knn20
  float* x1 = alloc(8 * 512 * 3);          // x2/x3/x4 are per-batch PREFIXES of x1
  float* f1 = alloc(8 * 512 * 64);         // f1..f4,g3,g2,g1 contiguous: one memset
  float* f2 = alloc(8 * 256 * 128);
  float* f3 = alloc(8 * 128 * 256);
  float* f4 = alloc(8 * 64 * 512);
  float* g3 = alloc(8 * 128 * 512);        // split-K raw accum (finalized by FP2 gather)
  float* g2 = alloc(8 * 256 * 256);        // split-K raw accum (finalized by FP1 gather)
  float* g1 = alloc(8 * 512 * 128);        // split-K raw accum (finalized by FP0 gather)
  float* g0 = alloc(8 * 4096 * 128);
  int* nidx1 = (int*)alloc(8 * 512 * 20);
  int* nidx2 = (int*)alloc(8 * 256 * 20);
  int* nidx3 = (int*)alloc(8 * 128 * 20);
  int* nidx4 = (int*)alloc(8 * 64 * 20);
  int* idx3_3 = (int*)alloc(8 * 128 * 3);  float* w3_3 = alloc(8 * 128 * 3);
  int* idx3_2 = (int*)alloc(8 * 256 * 3);  float* w3_2 = alloc(8 * 256 * 3);
  int* idx3_1 = (int*)alloc(8 * 512 * 3);  float* w3_1 = alloc(8 * 512 * 3);
  int* idx3_0 = (int*)alloc(8 * 4096 * 3); float* w3_0 = alloc(8 * 4096 * 3);

  // zero f1..f4 (atomic-max targets) AND g3,g2,g1 (split-K atomicAdd targets).
  hipMemsetAsync(f1, 0,
                 ((size_t)8 * (512 * 64 + 256 * 128 + 128 * 256 + 64 * 512) +
                  (size_t)8 * (128 * 512 + 256 * 256 + 512 * 128)) * 4, stream);

  split_xyz_kernel<<<cdiv(8 * 4096, 256), 256, 0, stream>>>(x, xyz, nrm, xyz4);
  fps4_kernel<256, 16><<<8, 256, 0, stream>>>(xyz, 4096, 512, x1);
  knn20_kernel<<<8 * 512, 64, 0, stream>>>(x1, xyz4, nidx1);
  // SA1 direct (needs nidx1): one wave per group of 20
  sa1_kernel<<<1024, 256, 0, stream>>>(xyz, nrm, x1, nidx1, W0, b0, f1);
  neighbors_kernel<<<1052, 256, 0, stream>>>(xyz, x1, nidx2, nidx3, nidx4,
                                             idx3_3, w3_3, idx3_2, w3_2,
                                             idx3_1, w3_1, idx3_0, w3_0);

  // ---- SA2: Cin 67 -> 128 ----
  {
    dim3 grid(2, 8 * 256 * 20 / 128);
    gemm_sa_kernel<<<grid, 256, 0, stream>>>(x1, f1, x1, nidx2, W1, b1, f2,
                                             512, 512, 256, 512, 64,
                                             8 * 256 * 20, 128, 67);
  }
  // ---- SA3: Cin 131 -> 256 ----
  {
    dim3 grid(4, 8 * 128 * 20 / 128);
    gemm_sa_kernel<<<grid, 256, 0, stream>>>(x1, f2, x1, nidx3, W2, b2, f3,
                                             256, 512, 128, 512, 128,
                                             8 * 128 * 20, 256, 131);
  }
  // ---- SA4: Cin 259 -> 512 ----
  {
    dim3 grid(8, 8 * 64 * 20 / 128);
    gemm_sa_kernel<<<grid, 256, 0, stream>>>(x1, f3, x1, nidx4, W3, b3, f4,
                                             128, 512, 64, 512, 256,
                                             8 * 64 * 20, 512, 259);
  }

  // ---- FP3: split-K x4 (K=768 -> 4x192), raw sums into g3 ----
  {
    dim3 grid(8, 8 * 128 / 128, 4);
    gemm_fp_kernel<<<grid, 256, 0, stream>>>(f4, idx3_3, w3_3, f3, nullptr, nullptr, nullptr,
                                             nullptr, F3, fb3, g3, 128, 64, 512, 256, 0,
                                             1, 192, 8 * 128, 512, 768);
  }
  // ---- FP2: split-K x4 (K=640 -> 4x160); gather finalizes g3 with fb3+relu ----
  {
    dim3 grid(4, 8 * 256 / 128, 4);
    gemm_fp_kernel<<<grid, 256, 0, stream>>>(g3, idx3_2, w3_2, f2, nullptr, nullptr, nullptr,
                                             fb3, F2, fb2, g2, 256, 128, 512, 128, 0,
                                             1, 160, 8 * 256, 256, 640);
  }
  // ---- FP1: split-K x4 (K=320 -> 4x80); gather finalizes g2 with fb2+relu ----
  {
    dim3 grid(2, 8 * 512 / 128, 4);
    gemm_fp_kernel<<<grid, 256, 0, stream>>>(g2, idx3_1, w3_1, f1, nullptr, nullptr, nullptr,
                                             fb2, F1, fb1, g1, 512, 256, 256, 64, 0,
                                             1, 80, 8 * 512, 128, 320);
  }
  // ---- FP0: no split (512 blocks); gather finalizes g1 with fb1+relu ----
  {
    dim3 grid(2, 8 * 4096 / 128, 1);
    gemm_fp_kernel<<<grid, 256, 0, stream>>>(g1, idx3_0, w3_0, nullptr, cls, xyz, nrm,
                                             fb1, F0, fb0, g0, 4096, 512, 128, 22, 1,
                                             0, 160, 8 * 4096, 128, 150);
  }

  // ---- seg head ----
  {
    dim3 grid(1, 8 * 4096 / 128);
    gemm_kernel<<<grid, 256, 0, stream>>>(g0, Wseg, bseg, out, 8 * 4096, 50, 128, 0);
  }
  // ---- out2 = transpose(g0) ----
  transpose_g0_kernel<<<dim3(128, 4, 8), 256, 0, stream>>>(g0, out + (size_t)8 * 4096 * 50);
}

// Round 8
// 956.453 us; speedup vs baseline: 1.1352x; 1.1352x over previous
//
#include <hip/hip_runtime.h>
#include <float.h>

#define B8 8
#define NPTS 4096

// ---------------- DPP helpers ----------------
template <int CTRL, int RM>
__device__ __forceinline__ unsigned dppmov(unsigned v) {
  return (unsigned)__builtin_amdgcn_update_dpp((int)v, (int)v, CTRL, RM, 0xf, false);
}

template <int CTRL, int RM>
__device__ __forceinline__ void red_key_max(unsigned& kh, unsigned& kl) {
  unsigned oh = dppmov<CTRL, RM>(kh);
  unsigned ol = dppmov<CTRL, RM>(kl);
  unsigned long long ko = ((unsigned long long)oh << 32) | ol;
  unsigned long long k  = ((unsigned long long)kh << 32) | kl;
  bool c = ko > k;
  kh = c ? oh : kh;
  kl = c ? ol : kl;
}

template <int CTRL, int RM>
__device__ __forceinline__ void red_key_min(unsigned& kh, unsigned& kl) {
  unsigned oh = dppmov<CTRL, RM>(kh);
  unsigned ol = dppmov<CTRL, RM>(kl);
  unsigned long long ko = ((unsigned long long)oh << 32) | ol;
  unsigned long long k  = ((unsigned long long)kh << 32) | kl;
  bool c = ko < k;
  kh = c ? oh : kh;
  kl = c ? ol : kl;
}

#define WAVE_RED_MAX(kh, kl)            \
  red_key_max<0x111, 0xf>(kh, kl);      \
  red_key_max<0x112, 0xf>(kh, kl);      \
  red_key_max<0x114, 0xf>(kh, kl);      \
  red_key_max<0x118, 0xf>(kh, kl);      \
  red_key_max<0x142, 0xa>(kh, kl);      \
  red_key_max<0x143, 0xc>(kh, kl);

#define WAVE_RED_MIN(kh, kl)            \
  red_key_min<0x111, 0xf>(kh, kl);      \
  red_key_min<0x112, 0xf>(kh, kl);      \
  red_key_min<0x114, 0xf>(kh, kl);      \
  red_key_min<0x118, 0xf>(kh, kl);      \
  red_key_min<0x142, 0xa>(kh, kl);      \
  red_key_min<0x143, 0xc>(kh, kl);

// ---------------- FPS + fused split (SA1 only; deeper levels are prefixes) ----------------
// R8: split_xyz fused into the load phase — channel-major reads from x are
// perfectly coalesced (better than the stride-12 xyz reads they replace);
// writes xyz/nrm/xyz4 as a side effect. FPS core unchanged (R1/R2: BLOCK=256/
// P=16, 1 wave/SIMD is the structural optimum, measured 320us).
template <int BLOCK, int P>
__global__ __launch_bounds__(BLOCK) void fps4_kernel(const float* __restrict__ x,
                                                     float* __restrict__ xyz,
                                                     float* __restrict__ nrm,
                                                     float4* __restrict__ xyz4,
                                                     int N, int S,
                                                     float* __restrict__ out_xyz) {
#pragma clang fp contract(off)
  constexpr int NW = BLOCK / 64;
  __shared__ float4 pts[BLOCK * P];
  __shared__ float4 sel[512];
  __shared__ alignas(16) unsigned long long wkey[2][NW];
  int b = blockIdx.x, t = threadIdx.x;
  const float* xb = x + (size_t)b * 6 * N;
  float px[P], py[P], pz[P], dist[P];
#pragma unroll
  for (int j = 0; j < P; ++j) {
    int idx = t + j * BLOCK;
    float a = xb[0 * N + idx], bb = xb[1 * N + idx], c = xb[2 * N + idx];
    px[j] = a; py[j] = bb; pz[j] = c;
    pts[idx] = make_float4(a, bb, c, 0.f);
    dist[j] = 1e10f;
    size_t g = (size_t)b * N + idx;
    float* o1 = xyz + g * 3;
    o1[0] = a; o1[1] = bb; o1[2] = c;
    xyz4[g] = make_float4(a, bb, c, a * a + bb * bb + c * c);
    float n0 = xb[3 * N + idx], n1 = xb[4 * N + idx], n2 = xb[5 * N + idx];
    float* o2 = nrm + g * 3;
    o2[0] = n0; o2[1] = n1; o2[2] = n2;
  }
  __syncthreads();
  float fx = xb[0], fy = xb[N], fz = xb[2 * N];
  for (int i = 0; i < S; ++i) {
    if (t == 0) sel[i] = make_float4(fx, fy, fz, 0.f);
    float bv = -1.0f;
    int bj = 0;
#pragma unroll
    for (int j = 0; j < P; ++j) {
      float dx = px[j] - fx, dy = py[j] - fy, dz = pz[j] - fz;
      float d = dx * dx + dy * dy + dz * dz;
      float nd = fminf(dist[j], d);
      dist[j] = nd;
      bool c = nd > bv;
      bv = c ? nd : bv;
      bj = c ? j : bj;
    }
    unsigned kh = __float_as_uint(bv);
    unsigned kl = (unsigned)(~(t + bj * BLOCK));
    WAVE_RED_MAX(kh, kl);
    int buf = i & 1;
    if ((t & 63) == 63)
      wkey[buf][t >> 6] = ((unsigned long long)kh << 32) | kl;
    __syncthreads();
    unsigned long long g = 0ull;
    const ulonglong2* wk2 = (const ulonglong2*)&wkey[buf][0];
#pragma unroll
    for (int w = 0; w < NW / 2; ++w) {
      ulonglong2 e = wk2[w];
      unsigned long long m = (e.x > e.y) ? e.x : e.y;
      g = (m > g) ? m : g;
    }
    int far = (int)~(unsigned)g;
    float4 f = pts[far];
    fx = f.x; fy = f.y; fz = f.z;
  }
  __syncthreads();
  for (int i = t; i < S; i += BLOCK) {
    float4 f = sel[i];
    float* o = out_xyz + ((size_t)b * S + i) * 3;
    o[0] = f.x; o[1] = f.y; o[2] = f.z;
  }
}

// ---------------- kNN k=20 + fused SA1 (M=4096, one wave/block) ----------------
// R6 min1/min2 cache selection; R8: SA1 MLP+maxpool fused in the tail.
// Lane k holds neighbor-k's index in `keep` after selection -> stage rel3/nrm3
// into 640B LDS and compute the 64-column MLP directly (same ascending-k
// separate mul/add order and max-over-20 as the standalone sa1). nidx1
// eliminated entirely (it had exactly one consumer).
__global__ __launch_bounds__(64) void knn20_kernel(const float* __restrict__ q,
                                                   const float4* __restrict__ ref4,
                                                   const float* __restrict__ nrm,
                                                   const float* __restrict__ W,
                                                   const float* __restrict__ bias,
                                                   float* __restrict__ f1) {
#pragma clang fp contract(off)
  int bs = blockIdx.x;                 // b*512 + s  (== group id)
  int b = bs >> 9;
  int t = threadIdx.x;
  __shared__ float sd[4096];
  __shared__ alignas(16) float smem_in[20][8];
  const float* qp = q + (size_t)bs * 3;
  float qx = qp[0], qy = qp[1], qz = qp[2];
  float qq = qx * qx + qy * qy + qz * qz;
  const float4* rp = ref4 + (size_t)b * 4096;
  float v1 = FLT_MAX, v2 = FLT_MAX;
  int i1 = 0, i2 = 0;
  for (int k = 0; k < 64; ++k) {
    int i = t + (k << 6);
    float4 r = rp[i];
    float dot = qx * r.x + qy * r.y + qz * r.z;
    float d = qq - 2.0f * dot + r.w;
    sd[i] = d;
    if (d < v1) { v2 = v1; i2 = i1; v1 = d; i1 = i; }
    else if (d < v2) { v2 = d; i2 = i; }
  }
  __syncthreads();
  unsigned keep = 0;
  for (int k = 0; k < 20; ++k) {
    unsigned kh = __float_as_uint(v1), kl = (unsigned)i1;
    WAVE_RED_MIN(kh, kl);
    unsigned w = (unsigned)__builtin_amdgcn_readlane((int)kl, 63);
    if (t == k) keep = w;
    if (t == 0) sd[w] = FLT_MAX;
    __syncthreads();                   // sd[w] visible before any rescan
    if (((int)w & 63) == t) {          // I owned the winner (w == my i1)
      v1 = v2; i1 = i2;
      v2 = FLT_MAX; i2 = 0;
      if (v1 == FLT_MAX) {             // cache exhausted: rebuild from sd
        for (int kk = 0; kk < 64; ++kk) {
          int i = t + (kk << 6);
          float d = sd[i];
          if (d < v1) { v2 = v1; i2 = i1; v1 = d; i1 = i; }
          else if (d < v2) { v2 = d; i2 = i; }
        }
      }
    }
  }
  // ---- fused SA1: lane n<20 stages its neighbor; all 64 lanes = output cols ----
  if (t < 20) {
    int id = (int)keep;
    float4 r = rp[id];                 // (x,y,z,|p|^2)
    const float* nr = nrm + ((size_t)b * 4096 + id) * 3;
    smem_in[t][0] = r.x - qx;
    smem_in[t][1] = r.y - qy;
    smem_in[t][2] = r.z - qz;
    smem_in[t][3] = nr[0];
    smem_in[t][4] = nr[1];
    smem_in[t][5] = nr[2];
    smem_in[t][6] = 0.0f;
    smem_in[t][7] = 0.0f;
  }
  __syncthreads();
  float w0 = W[0 * 64 + t], w1 = W[1 * 64 + t], w2 = W[2 * 64 + t];
  float w3 = W[3 * 64 + t], w4 = W[4 * 64 + t], w5 = W[5 * 64 + t];
  float bb = bias[t];
  float m = 0.0f;                      // relu >= 0: 0-init absorbs the relu clamp
  for (int n = 0; n < 20; ++n) {
    const float4 a = *reinterpret_cast<const float4*>(&smem_in[n][0]);
    const float4 c = *reinterpret_cast<const float4*>(&smem_in[n][4]);
    float v = a.x * w0;
    v += a.y * w1;
    v += a.z * w2;
    v += a.w * w3;
    v += c.x * w4;
    v += c.y * w5;
    v += bb;
    m = fmaxf(m, v);
  }
  f1[(size_t)bs * 64 + t] = m;
}

// ---------------- knn3 select+store helper ----------------
__device__ __forceinline__ void knn3_store(int g, const float* rx3,
                                           float qx, float qy, float qz,
                                           int i0, int i1, int i2,
                                           int* __restrict__ idx3,
                                           float* __restrict__ w3) {
#pragma clang fp contract(off)
  int ii[3] = {i0, i1, i2};
  float w[3];
  float wsum = 0.0f;
#pragma unroll
  for (int k = 0; k < 3; ++k) {
    const float* r = rx3 + (size_t)ii[k] * 3;
    float dx = r[0] - qx, dy = r[1] - qy, dz = r[2] - qz;
    float d = dx * dx + dy * dy + dz * dz;
    w[k] = 1.0f / (d + 1e-8f);
    wsum += w[k];
  }
#pragma unroll
  for (int k = 0; k < 3; ++k) {
    idx3[(size_t)g * 3 + k] = ii[k];
    w3[(size_t)g * 3 + k] = w[k] / wsum;
  }
}

// ---------------- fused neighbor kernel: SA2/3/4 knn20 + all knn3 ----------------
__global__ __launch_bounds__(256) void neighbors_kernel(
    const float* __restrict__ xyz, const float* __restrict__ x1,
    int* __restrict__ nidx2, int* __restrict__ nidx3, int* __restrict__ nidx4,
    int* __restrict__ idx3_3, float* __restrict__ w3_3,
    int* __restrict__ idx3_2, float* __restrict__ w3_2,
    int* __restrict__ idx3_1, float* __restrict__ w3_1,
    int* __restrict__ idx3_0, float* __restrict__ w3_0) {
#pragma clang fp contract(off)
  __shared__ float4 smem4[512];          // 8 KB, aliased per region
  int blk = blockIdx.x, tid = threadIdx.x;

  if (blk < 896) {  // ---- knn20 regions ----
    int S, M, qid;
    int* nout;
    const int wv = tid >> 6, t64 = tid & 63;
    if (blk < 512)      { S = 256; M = 512; qid = blk * 4 + wv;         nout = nidx2; }
    else if (blk < 768) { S = 128; M = 256; qid = (blk - 512) * 4 + wv; nout = nidx3; }
    else                { S = 64;  M = 128; qid = (blk - 768) * 4 + wv; nout = nidx4; }
    float* swd = (float*)smem4 + wv * M;
    int b = qid / S, s = qid % S;
    const float* qp = x1 + ((size_t)b * 512 + s) * 3;
    float qx = qp[0], qy = qp[1], qz = qp[2];
    float qq = qx * qx + qy * qy + qz * qz;
    const float* rp = x1 + (size_t)b * 512 * 3;
    for (int i = t64; i < M; i += 64) {
      float rx = rp[3 * i], ry = rp[3 * i + 1], rz = rp[3 * i + 2];
      float rr = rx * rx + ry * ry + rz * rz;
      float dot = qx * rx + qy * ry + qz * rz;
      swd[i] = qq - 2.0f * dot + rr;
    }
    __syncthreads();
    unsigned keep = 0;
    for (int k = 0; k < 20; ++k) {
      float bv = FLT_MAX;
      int bi = 0;
      for (int i = t64; i < M; i += 64) {
        float v = swd[i];
        bool c = v < bv;
        bv = c ? v : bv;
        bi = c ? i : bi;
      }
      unsigned kh = __float_as_uint(bv), kl = (unsigned)bi;
      WAVE_RED_MIN(kh, kl);
      unsigned w = (unsigned)__builtin_amdgcn_readlane((int)kl, 63);
      if (t64 == k) keep = w;
      if (t64 == 0) swd[w] = FLT_MAX;
      __syncthreads();   // uniform across the block's 4 waves (same trip count)
    }
    if (t64 < 20) nout[(size_t)qid * 20 + t64] = (int)keep;
    return;
  }

  if (blk < 900) {  // ---- FP3 knn3, plain VMEM scan (M=64) ----
    int g = (blk - 896) * 256 + tid;     // < 1024
    int Sq = 128, M = 64;
    int b = g / Sq, s = g % Sq;
    const float* qp = x1 + ((size_t)b * 512 + s) * 3;
    float qx = qp[0], qy = qp[1], qz = qp[2];
    float qq = qx * qx + qy * qy + qz * qz;
    const float* rp = x1 + (size_t)b * 512 * 3;
    float v0 = FLT_MAX, v1 = FLT_MAX, v2 = FLT_MAX;
    int i0 = 0, i1 = 0, i2 = 0;
    for (int i = 0; i < M; ++i) {
      float rx = rp[3 * i], ry = rp[3 * i + 1], rz = rp[3 * i + 2];
      float d = qq - 2.0f * (qx * rx + qy * ry + qz * rz) + (rx * rx + ry * ry + rz * rz);
      if (d < v2) {
        if (d < v1) {
          if (d < v0) { v2 = v1; i2 = i1; v1 = v0; i1 = i0; v0 = d; i0 = i; }
          else { v2 = v1; i2 = i1; v1 = d; i1 = i; }
        } else { v2 = d; i2 = i; }
      }
    }
    knn3_store(g, rp, qx, qy, qz, i0, i1, i2, idx3_3, w3_3);
    return;
  }

  // ---- knn3 LDS regions (block-uniform batch) ----
  int g, Sq, M, LDQ;
  int* oidx;
  float* ow;
  const float* q;
  if (blk < 908)      { g = (blk - 900) * 256 + tid; Sq = 256;  M = 128; oidx = idx3_2; ow = w3_2; q = x1;  LDQ = 512; }
  else if (blk < 924) { g = (blk - 908) * 256 + tid; Sq = 512;  M = 256; oidx = idx3_1; ow = w3_1; q = x1;  LDQ = 512; }
  else                { g = (blk - 924) * 256 + tid; Sq = 4096; M = 512; oidx = idx3_0; ow = w3_0; q = xyz; LDQ = 4096; }
  int b = g / Sq, s = g % Sq;
  const float* rp = x1 + (size_t)b * 512 * 3;
  for (int i = tid; i < M; i += 256) {
    float rx = rp[3 * i], ry = rp[3 * i + 1], rz = rp[3 * i + 2];
    smem4[i] = make_float4(rx, ry, rz, rx * rx + ry * ry + rz * rz);
  }
  __syncthreads();
  const float* qp = q + ((size_t)b * LDQ + s) * 3;
  float qx = qp[0], qy = qp[1], qz = qp[2];
  float qq = qx * qx + qy * qy + qz * qz;
  float v0 = FLT_MAX, v1 = FLT_MAX, v2 = FLT_MAX;
  int i0 = 0, i1 = 0, i2 = 0;
  for (int i = 0; i < M; ++i) {
    float4 r = smem4[i];
    float d = qq - 2.0f * (qx * r.x + qy * r.y + qz * r.z) + r.w;
    if (d < v2) {
      if (d < v1) {
        if (d < v0) { v2 = v1; i2 = i1; v1 = v0; i1 = i0; v0 = d; i0 = i; }
        else { v2 = v1; i2 = i1; v1 = d; i1 = i; }
      } else { v2 = d; i2 = i; }
    }
  }
  {
    int ii[3] = {i0, i1, i2};
    float w[3];
    float wsum = 0.0f;
#pragma unroll
    for (int k = 0; k < 3; ++k) {
      float4 r = smem4[ii[k]];
      float dx = r.x - qx, dy = r.y - qy, dz = r.z - qz;
      float d = dx * dx + dy * dy + dz * dz;
      w[k] = 1.0f / (d + 1e-8f);
      wsum += w[k];
    }
#pragma unroll
    for (int k = 0; k < 3; ++k) {
      oidx[(size_t)g * 3 + k] = ii[k];
      ow[(size_t)g * 3 + k] = w[k] / wsum;
    }
  }
}

// ---------------- double-buffered GEMM core (R6: 64x64, BK=16, row-quad) ----------------
// R7 lesson: bigger tiles lengthen the per-thread gather chain and halve TLP
// -> stage latency exposed, net regression. 64x64/row-quad is the empirical
// optimum for these gather-fed GEMMs.
#define GEMM_STAGE(k0v, ...)                                                      \
    {                                                                             \
      int r_ = (int)threadIdx.x & 63;                                             \
      int ks_ = (int)threadIdx.x >> 6;                                            \
      int rr = rowBase + r_;                                                      \
      int kq0 = (k0v) + ks_ * 4;                                                  \
      float4 va = make_float4(0.f, 0.f, 0.f, 0.f);                                \
      if (rr < Mrows) { __VA_ARGS__ }                                             \
      areg4 = va;                                                                 \
    }                                                                             \
    {                                                                             \
      int kk = (int)threadIdx.x >> 4;                                             \
      int n4 = ((int)threadIdx.x & 15) * 4;                                       \
      int kq = (k0v) + kk, cc = colBase + n4;                                     \
      if (colBase + 64 <= N) {                                                    \
        if (kq < K) breg4 = *reinterpret_cast<const float4*>(&Wm[(size_t)kq * N + cc]); \
        else breg4 = make_float4(0.f, 0.f, 0.f, 0.f);                             \
      } else {                                                                    \
        breg4.x = (kq < K && cc < N) ? Wm[(size_t)kq * N + cc] : 0.0f;            \
        breg4.y = (kq < K && cc + 1 < N) ? Wm[(size_t)kq * N + cc + 1] : 0.0f;    \
        breg4.z = (kq < K && cc + 2 < N) ? Wm[(size_t)kq * N + cc + 2] : 0.0f;    \
        breg4.w = (kq < K && cc + 3 < N) ? Wm[(size_t)kq * N + cc + 3] : 0.0f;    \
      }                                                                           \
    }

#define GEMM_WRITE_LDS(bufv)                                                      \
    {                                                                             \
      int r_ = (int)threadIdx.x & 63;                                             \
      int k4_ = ((int)threadIdx.x >> 6) * 4;                                      \
      As[bufv][k4_ + 0][r_] = areg4.x;                                            \
      As[bufv][k4_ + 1][r_] = areg4.y;                                            \
      As[bufv][k4_ + 2][r_] = areg4.z;                                            \
      As[bufv][k4_ + 3][r_] = areg4.w;                                            \
    }                                                                             \
    *reinterpret_cast<float4*>(&Bs[bufv][threadIdx.x >> 4][(threadIdx.x & 15) * 4]) = breg4;

#define GEMM_MAIN(...)                                                            \
  __shared__ alignas(16) float As[2][16][68];                                     \
  __shared__ alignas(16) float Bs[2][16][64];                                     \
  int tx = threadIdx.x & 15, ty = threadIdx.x >> 4;                               \
  int rowBase = blockIdx.y * 64;                                                  \
  int colBase = blockIdx.x * 64;                                                  \
  float acc[4][4] = {};                                                           \
  float4 areg4, breg4;                                                            \
  GEMM_STAGE(kLo, __VA_ARGS__)                                                    \
  GEMM_WRITE_LDS(0)                                                               \
  __syncthreads();                                                                \
  int cur = 0;                                                                    \
  for (int k0 = kLo; k0 < kHi; k0 += 16) {                                        \
    int nxt = cur ^ 1;                                                            \
    bool more = (k0 + 16 < kHi);                                                  \
    if (more) { GEMM_STAGE(k0 + 16, __VA_ARGS__) }                                \
    _Pragma("unroll")                                                             \
    for (int kk = 0; kk < 16; ++kk) {                                             \
      const float4 av = *reinterpret_cast<const float4*>(&As[cur][kk][ty * 4]);   \
      const float4 bv = *reinterpret_cast<const float4*>(&Bs[cur][kk][tx * 4]);   \
      acc[0][0] += av.x * bv.x; acc[0][1] += av.x * bv.y;                         \
      acc[0][2] += av.x * bv.z; acc[0][3] += av.x * bv.w;                         \
      acc[1][0] += av.y * bv.x; acc[1][1] += av.y * bv.y;                         \
      acc[1][2] += av.y * bv.z; acc[1][3] += av.y * bv.w;                         \
      acc[2][0] += av.z * bv.x; acc[2][1] += av.z * bv.y;                         \
      acc[2][2] += av.z * bv.z; acc[2][3] += av.z * bv.w;                         \
      acc[3][0] += av.w * bv.x; acc[3][1] += av.w * bv.y;                         \
      acc[3][2] += av.w * bv.z; acc[3][3] += av.w * bv.w;                         \
    }                                                                             \
    if (more) { GEMM_WRITE_LDS(nxt) }                                             \
    __syncthreads();                                                              \
    cur = nxt;                                                                    \
  }

#define GEMM_EPI_STORE                                                            \
  _Pragma("unroll")                                                               \
  for (int i = 0; i < 4; ++i) {                                                   \
    int row = rowBase + ty * 4 + i;                                               \
    if (row >= Mrows) continue;                                                   \
    _Pragma("unroll")                                                             \
    for (int j = 0; j < 4; ++j) {                                                 \
      int col = colBase + tx * 4 + j;                                             \
      if (col >= N) continue;                                                     \
      float v = acc[i][j] + bias[col];                                            \
      if (RELU) v = fmaxf(v, 0.0f);                                               \
      C[(size_t)row * N + col] = v;                                               \
    }                                                                             \
  }

// seg head GEMM + fused transpose side-write: every g0 element is staged
// exactly once across the k0 loop -> write out2[b][k][n] at stage time.
// K=128 always here (kq0 <= 124, so the quad load is in-range).
__global__ __launch_bounds__(256) void gemm_seg_kernel(const float* __restrict__ A,
                                                       const float* __restrict__ Wm,
                                                       const float* __restrict__ bias,
                                                       float* __restrict__ C,
                                                       float* __restrict__ T,
                                                       int Mrows, int N, int K) {
  const int kLo = 0, kHi = K;
  const int RELU = 0;
  GEMM_MAIN(
    va = *reinterpret_cast<const float4*>(&A[(size_t)rr * K + kq0]);
    {
      int n_ = rr & 4095, b_ = rr >> 12;
      float* tp = T + (((size_t)b_ * 128 + kq0) * 4096 + n_);
      tp[0] = va.x; tp[4096] = va.y; tp[8192] = va.z; tp[12288] = va.w;
    }
  )
  GEMM_EPI_STORE
}

// SA GEMM (SA2-4): fused grouping gather + ReLU + maxpool-over-20 via atomic-max.
// fOut must be zero-initialized; relu >= 0 so float-bit int max == float max.
__global__ __launch_bounds__(256) void gemm_sa_kernel(
    const float* __restrict__ xyz, const float* __restrict__ feats,
    const float* __restrict__ new_xyz, const int* __restrict__ nidx,
    const float* __restrict__ Wm, const float* __restrict__ bias,
    float* __restrict__ fOut, int Mref, int LDR, int S, int LDQ, int Cf,
    int Mrows, int N, int K) {
  const int kLo = 0, kHi = K;
  GEMM_MAIN(
    int bs = rr / 20;
    int s_ = bs % S;
    int b = bs / S;
    int id = nidx[rr];
    const float* xr_ = xyz + ((size_t)b * LDR + id) * 3;
    const float* xq_ = new_xyz + ((size_t)b * LDQ + s_) * 3;
    const float* fb_ = feats + ((size_t)b * Mref + id) * Cf;
    float* vp_ = (float*)&va;
    _Pragma("unroll")
    for (int c_ = 0; c_ < 4; ++c_) {
      int kq = kq0 + c_;
      float v = 0.0f;
      if (kq < K) v = (kq < 3) ? (xr_[kq] - xq_[kq]) : fb_[kq - 3];
      vp_[c_] = v;
    }
  )
  // epilogue: rows in aligned quads, 20 % 4 == 0 -> each thread's 4 rows are
  // one group: register pre-max then ONE atomic per column.
  __shared__ int smax[4][64];
  int gBase = rowBase / 20;
  int nG = (rowBase + 63) / 20 - gBase + 1;
  for (int l = threadIdx.x; l < nG * 64; l += 256) smax[l >> 6][l & 63] = 0;
  __syncthreads();
  {
    int gl = (rowBase + ty * 4) / 20 - gBase;
#pragma unroll
    for (int j = 0; j < 4; ++j) {
      int col = colBase + tx * 4 + j;
      if (col >= N) continue;
      float bb = bias[col];
      float m = 0.0f;
#pragma unroll
      for (int i = 0; i < 4; ++i) {
        int row = rowBase + ty * 4 + i;
        if (row >= Mrows) continue;
        m = fmaxf(m, fmaxf(acc[i][j] + bb, 0.0f));
      }
      atomicMax(&smax[gl][tx * 4 + j], __float_as_int(m));
    }
  }
  __syncthreads();
  for (int l = threadIdx.x; l < nG * 64; l += 256) {
    int g = gBase + (l >> 6), c = colBase + (l & 63);
    if (c < N) atomicMax((int*)&fOut[(size_t)g * N + c], smax[l >> 6][l & 63]);
  }
}

// FP GEMM with fused 3-NN interp + skip concat; split-K + consumer finalize.
__global__ __launch_bounds__(256) void gemm_fp_kernel(
    const float* __restrict__ fr, const int* __restrict__ idx3,
    const float* __restrict__ w3, const float* __restrict__ skip,
    const float* __restrict__ cls, const float* __restrict__ xyzq,
    const float* __restrict__ nrmq, const float* __restrict__ frBias,
    const float* __restrict__ Wm, const float* __restrict__ bias,
    float* __restrict__ C, int Sq, int Mr, int Cr, int Cs, int mode,
    int SPLITK, int CHUNK,
    int Mrows, int N, int K) {
  const int kLo = blockIdx.z * CHUNK;
  const int kHi = min(K, kLo + CHUNK);
  GEMM_MAIN(
    int bs = rr;
    int b = bs / Sq;
    const int* ii_ = idx3 + (size_t)bs * 3;
    const float* ww_ = w3 + (size_t)bs * 3;
    int i0_ = ii_[0], i1_ = ii_[1], i2_ = ii_[2];
    float w0_ = ww_[0], w1_ = ww_[1], w2_ = ww_[2];
    const float* fb_ = fr + (size_t)b * Mr * Cr;
    float* vp_ = (float*)&va;
    _Pragma("unroll")
    for (int c_ = 0; c_ < 4; ++c_) {
      int kq = kq0 + c_;
      float v = 0.0f;
      if (kq < K) {
        if (kq < Cr) {
          float a0 = fb_[(size_t)i0_ * Cr + kq];
          float a1 = fb_[(size_t)i1_ * Cr + kq];
          float a2 = fb_[(size_t)i2_ * Cr + kq];
          if (frBias) {
            float bb = frBias[kq];
            a0 = fmaxf(a0 + bb, 0.0f);
            a1 = fmaxf(a1 + bb, 0.0f);
            a2 = fmaxf(a2 + bb, 0.0f);
          }
          v = w0_ * a0;
          v += w1_ * a1;
          v += w2_ * a2;
        } else {
          int cc = kq - Cr;
          if (mode == 0) {
            v = skip[(size_t)bs * Cs + cc];
          } else {
            if (cc < 16) v = cls[(size_t)b * 16 + cc];
            else if (cc < 19) v = xyzq[(size_t)bs * 3 + (cc - 16)];
            else v = nrmq[(size_t)bs * 3 + (cc - 19)];
          }
        }
      }
      vp_[c_] = v;
    }
  )
  if (SPLITK) {
#pragma unroll
    for (int i = 0; i < 4; ++i) {
      int row = rowBase + ty * 4 + i;
      if (row >= Mrows) continue;
#pragma unroll
      for (int j = 0; j < 4; ++j) {
        int col = colBase + tx * 4 + j;
        if (col >= N) continue;
        atomicAdd(&C[(size_t)row * N + col], acc[i][j]);
      }
    }
  } else {
    const int RELU = 1;
    GEMM_EPI_STORE
  }
}

// ---------------- host-side orchestration ----------------
static inline int cdiv(int a, int b) { return (a + b - 1) / b; }

extern "C" void kernel_launch(void* const* d_in, const int* in_sizes, int n_in,
                              void* d_out, int out_size, void* d_ws, size_t ws_size,
                              hipStream_t stream) {
  const float* x    = (const float*)d_in[0];
  const float* cls  = (const float*)d_in[1];
  const float* W0 = (const float*)d_in[2];  const float* b0 = (const float*)d_in[3];
  const float* W1 = (const float*)d_in[4];  const float* b1 = (const float*)d_in[5];
  const float* W2 = (const float*)d_in[6];  const float* b2 = (const float*)d_in[7];
  const float* W3 = (const float*)d_in[8];  const float* b3 = (const float*)d_in[9];
  const float* F3 = (const float*)d_in[10]; const float* fb3 = (const float*)d_in[11];
  const float* F2 = (const float*)d_in[12]; const float* fb2 = (const float*)d_in[13];
  const float* F1 = (const float*)d_in[14]; const float* fb1 = (const float*)d_in[15];
  const float* F0 = (const float*)d_in[16]; const float* fb0 = (const float*)d_in[17];
  const float* Wseg = (const float*)d_in[18]; const float* bseg = (const float*)d_in[19];
  float* out = (float*)d_out;

  float* ws = (float*)d_ws;
  size_t off = 0;
  auto alloc = [&](size_t n) { float* p = ws + off; off += (n + 3) & ~(size_t)3; return p; };
  float* xyz = alloc(8 * 4096 * 3);
  float* nrm = alloc(8 * 4096 * 3);
  float4* xyz4 = (float4*)alloc(8 * 4096 * 4);   // (x,y,z,|p|^2) for knn20
  float* x1 = alloc(8 * 512 * 3);          // x2/x3/x4 are per-batch PREFIXES of x1
  float* f1 = alloc(8 * 512 * 64);         // f1..f4,g3,g2,g1 contiguous: one memset
  float* f2 = alloc(8 * 256 * 128);
  float* f3 = alloc(8 * 128 * 256);
  float* f4 = alloc(8 * 64 * 512);
  float* g3 = alloc(8 * 128 * 512);        // split-K raw accum (finalized by FP2 gather)
  float* g2 = alloc(8 * 256 * 256);        // split-K raw accum (finalized by FP1 gather)
  float* g1 = alloc(8 * 512 * 128);        // split-K raw accum (finalized by FP0 gather)
  float* g0 = alloc(8 * 4096 * 128);
  int* nidx2 = (int*)alloc(8 * 256 * 20);
  int* nidx3 = (int*)alloc(8 * 128 * 20);
  int* nidx4 = (int*)alloc(8 * 64 * 20);
  int* idx3_3 = (int*)alloc(8 * 128 * 3);  float* w3_3 = alloc(8 * 128 * 3);
  int* idx3_2 = (int*)alloc(8 * 256 * 3);  float* w3_2 = alloc(8 * 256 * 3);
  int* idx3_1 = (int*)alloc(8 * 512 * 3);  float* w3_1 = alloc(8 * 512 * 3);
  int* idx3_0 = (int*)alloc(8 * 4096 * 3); float* w3_0 = alloc(8 * 4096 * 3);

  // zero f1..f4 (atomic-max targets; f1 now direct-stored but harmless) AND
  // g3,g2,g1 (split-K atomicAdd targets). Contiguous by construction.
  hipMemsetAsync(f1, 0,
                 ((size_t)8 * (512 * 64 + 256 * 128 + 128 * 256 + 64 * 512) +
                  (size_t)8 * (128 * 512 + 256 * 256 + 512 * 128)) * 4, stream);

  // fps with fused split: emits xyz/nrm/xyz4 + x1
  fps4_kernel<256, 16><<<8, 256, 0, stream>>>(x, xyz, nrm, xyz4, 4096, 512, x1);
  // knn20 with fused SA1: writes f1 directly (nidx1 eliminated)
  knn20_kernel<<<8 * 512, 64, 0, stream>>>(x1, xyz4, nrm, W0, b0, f1);
  neighbors_kernel<<<1052, 256, 0, stream>>>(xyz, x1, nidx2, nidx3, nidx4,
                                             idx3_3, w3_3, idx3_2, w3_2,
                                             idx3_1, w3_1, idx3_0, w3_0);

  // ---- SA2: Cin 67 -> 128 ----
  {
    dim3 grid(2, cdiv(8 * 256 * 20, 64));
    gemm_sa_kernel<<<grid, 256, 0, stream>>>(x1, f1, x1, nidx2, W1, b1, f2,
                                             512, 512, 256, 512, 64,
                                             8 * 256 * 20, 128, 67);
  }
  // ---- SA3: Cin 131 -> 256 ----
  {
    dim3 grid(4, cdiv(8 * 128 * 20, 64));
    gemm_sa_kernel<<<grid, 256, 0, stream>>>(x1, f2, x1, nidx3, W2, b2, f3,
                                             256, 512, 128, 512, 128,
                                             8 * 128 * 20, 256, 131);
  }
  // ---- SA4: Cin 259 -> 512 ----
  {
    dim3 grid(8, cdiv(8 * 64 * 20, 64));
    gemm_sa_kernel<<<grid, 256, 0, stream>>>(x1, f3, x1, nidx4, W3, b3, f4,
                                             128, 512, 64, 512, 256,
                                             8 * 64 * 20, 512, 259);
  }

  // ---- FP3: split-K x4 (K=768 -> 4x192), raw sums into g3 ----
  {
    dim3 grid(8, cdiv(8 * 128, 64), 4);
    gemm_fp_kernel<<<grid, 256, 0, stream>>>(f4, idx3_3, w3_3, f3, nullptr, nullptr, nullptr,
                                             nullptr, F3, fb3, g3, 128, 64, 512, 256, 0,
                                             1, 192, 8 * 128, 512, 768);
  }
  // ---- FP2: split-K x4 (K=640 -> 4x160); gather finalizes g3 with fb3+relu ----
  {
    dim3 grid(4, cdiv(8 * 256, 64), 4);
    gemm_fp_kernel<<<grid, 256, 0, stream>>>(g3, idx3_2, w3_2, f2, nullptr, nullptr, nullptr,
                                             fb3, F2, fb2, g2, 256, 128, 512, 128, 0,
                                             1, 160, 8 * 256, 256, 640);
  }
  // ---- FP1: split-K x2 (K=320 -> 2x160); gather finalizes g2 with fb2+relu ----
  {
    dim3 grid(2, cdiv(8 * 512, 64), 2);
    gemm_fp_kernel<<<grid, 256, 0, stream>>>(g2, idx3_1, w3_1, f1, nullptr, nullptr, nullptr,
                                             fb2, F1, fb1, g1, 512, 256, 256, 64, 0,
                                             1, 160, 8 * 512, 128, 320);
  }
  // ---- FP0: no split (1024 blocks); gather finalizes g1 with fb1+relu ----
  {
    dim3 grid(2, cdiv(8 * 4096, 64), 1);
    gemm_fp_kernel<<<grid, 256, 0, stream>>>(g1, idx3_0, w3_0, nullptr, cls, xyz, nrm,
                                             fb1, F0, fb0, g0, 4096, 512, 128, 22, 1,
                                             0, 160, 8 * 4096, 128, 150);
  }

  // ---- seg head + fused transpose (out2 written at stage time) ----
  {
    dim3 grid(1, cdiv(8 * 4096, 64));
    gemm_seg_kernel<<<grid, 256, 0, stream>>>(g0, Wseg, bseg, out,
                                              out + (size_t)8 * 4096 * 50,
                                              8 * 4096, 50, 128);
  }
}